// Round 7
// baseline (316.156 us; speedup 1.0000x reference)
//
#include <hip/hip_runtime.h>

#define NN 10000
#define EE 160000
#define DD 1024          // D_IN + H
#define FOURH 2048
#define HH 512
#define MT 20000         // B*N
#define MPAD 20224       // 79 * 256

typedef __attribute__((ext_vector_type(8))) short bf16x8;
typedef __attribute__((ext_vector_type(4))) float f32x4;

typedef __attribute__((address_space(1))) void gvoid;
typedef __attribute__((address_space(3))) void lvoid;

__device__ inline void gload16(const void* g, void* l) {
    __builtin_amdgcn_global_load_lds((gvoid*)g, (lvoid*)l, 16, 0, 0);
}

__device__ inline unsigned short f2bf(float f) {
    unsigned u = __float_as_uint(f);
    u += 0x7fff + ((u >> 16) & 1);   // RNE
    return (unsigned short)(u >> 16);
}

__device__ inline float bflo(unsigned u) { return __uint_as_float(u << 16); }
__device__ inline float bfhi(unsigned u) { return __uint_as_float(u & 0xffff0000u); }

__device__ inline float sigmoidf_(float x) {
    x = fminf(fmaxf(x, -30.f), 30.f);
    return 1.f / (1.f + __expf(-x));
}
__device__ inline float tanhf_(float x) {
    x = fminf(fmaxf(x, -15.f), 15.f);
    float e = __expf(2.f * x);
    return (e - 1.f) / (e + 1.f);
}

// ---------------- CSR build ----------------

__global__ void count_kernel(const int* __restrict__ dst, int* __restrict__ counts) {
    int e = blockIdx.x * blockDim.x + threadIdx.x;
    if (e < EE) atomicAdd(&counts[dst[e]], 1);
}

__global__ void scan_kernel(const int* __restrict__ counts, int* __restrict__ offsets,
                            int* __restrict__ cursor, float* __restrict__ dinv,
                            float* __restrict__ invdeg) {
    __shared__ int s[1024];
    int tid = threadIdx.x;
    int running = 0;
    if (tid == 0) offsets[0] = 0;
    for (int base = 0; base < NN; base += 1024) {
        int i = base + tid;
        int v = (i < NN) ? counts[i] : 0;
        s[tid] = v;
        __syncthreads();
        for (int off = 1; off < 1024; off <<= 1) {
            int t = (tid >= off) ? s[tid - off] : 0;
            __syncthreads();
            s[tid] += t;
            __syncthreads();
        }
        int incl = s[tid];
        if (i < NN) {
            offsets[i + 1] = running + incl;
            cursor[i] = running + incl - v;   // exclusive
            float deg = (float)(v + 1);
            dinv[i] = rsqrtf(deg);
            invdeg[i] = 1.0f / deg;
        }
        running += s[1023];
        __syncthreads();
    }
}

__global__ void fill_kernel(const int* __restrict__ src, const int* __restrict__ dst,
                            int* __restrict__ cursor, int* __restrict__ csr_src) {
    int e = blockIdx.x * blockDim.x + threadIdx.x;
    if (e < EE) {
        int p = atomicAdd(&cursor[dst[e]], 1);
        csr_src[p] = src[e];
    }
}

// ---------------- x,h -> packed bf16 rows xhc[n][2048] ----------------

__global__ __launch_bounds__(256) void convert_kernel(
    const float* __restrict__ x, const float* __restrict__ h,
    unsigned short* __restrict__ xhc)
{
    int n = blockIdx.x;
    int t = threadIdx.x;
    int sec = t >> 6;        // 0..3
    int li = t & 63;         // 8 floats each
    const float* srcp;
    if (sec == 0)      srcp = x + (size_t)n * 512 + li * 8;
    else if (sec == 1) srcp = h + (size_t)n * 512 + li * 8;
    else if (sec == 2) srcp = x + (size_t)(NN + n) * 512 + li * 8;
    else               srcp = h + (size_t)(NN + n) * 512 + li * 8;
    float4 v0 = *(const float4*)srcp;
    float4 v1 = *(const float4*)(srcp + 4);
    uint4 o;
    o.x = f2bf(v0.x) | ((unsigned)f2bf(v0.y) << 16);
    o.y = f2bf(v0.z) | ((unsigned)f2bf(v0.w) << 16);
    o.z = f2bf(v1.x) | ((unsigned)f2bf(v1.y) << 16);
    o.w = f2bf(v1.z) | ((unsigned)f2bf(v1.w) << 16);
    *(uint4*)(xhc + (size_t)n * 2048 + t * 8) = o;
}

__global__ void padzero_kernel(unsigned short* __restrict__ agg) {
    int idx = blockIdx.x * 256 + threadIdx.x;      // 224 rows * 1024 / 4 = 57344 ushort4
    ushort4* p = (ushort4*)(agg + (size_t)MT * DD);
    if (idx < 57344) p[idx] = make_ushort4(0, 0, 0, 0);
}

// ---------------- aggregation (bf16 gather, fp32 accumulate) ----------------

__global__ __launch_bounds__(256) void agg_kernel(
    const unsigned short* __restrict__ xhc,
    const int* __restrict__ csr_src, const int* __restrict__ offsets,
    const float* __restrict__ dinv, const float* __restrict__ invdeg,
    unsigned short* __restrict__ agg)
{
    int n = blockIdx.x;
    int t = threadIdx.x;                 // 8 bf16 per thread of the 2048-wide row
    const unsigned short* base = xhc + t * 8;
    float a0 = 0, a1 = 0, a2 = 0, a3 = 0, a4 = 0, a5 = 0, a6 = 0, a7 = 0;
    float dn = dinv[n];
    int beg = offsets[n], end = offsets[n + 1];
    for (int j = beg; j < end; ++j) {
        int s = csr_src[j];
        float w = dn * dinv[s];
        uint4 v = *(const uint4*)(base + (size_t)s * 2048);
        a0 += w * bflo(v.x); a1 += w * bfhi(v.x);
        a2 += w * bflo(v.y); a3 += w * bfhi(v.y);
        a4 += w * bflo(v.z); a5 += w * bfhi(v.z);
        a6 += w * bflo(v.w); a7 += w * bfhi(v.w);
    }
    float sw = invdeg[n];
    {
        uint4 v = *(const uint4*)(base + (size_t)n * 2048);
        a0 += sw * bflo(v.x); a1 += sw * bfhi(v.x);
        a2 += sw * bflo(v.y); a3 += sw * bfhi(v.y);
        a4 += sw * bflo(v.z); a5 += sw * bfhi(v.z);
        a6 += sw * bflo(v.w); a7 += sw * bfhi(v.w);
    }
    uint4 o;
    o.x = f2bf(a0) | ((unsigned)f2bf(a1) << 16);
    o.y = f2bf(a2) | ((unsigned)f2bf(a3) << 16);
    o.z = f2bf(a4) | ((unsigned)f2bf(a5) << 16);
    o.w = f2bf(a6) | ((unsigned)f2bf(a7) << 16);
    int bsel = t >> 7;                   // batch
    int d = (t & 127) * 8;               // dim within 1024
    *(uint4*)(agg + ((size_t)(bsel * NN + n)) * DD + d) = o;
}

// ---------------- W transpose -> bf16 (Wt[j][k]) ----------------

__global__ __launch_bounds__(256) void wt_kernel(const float* __restrict__ W,
                                                 unsigned short* __restrict__ Wt) {
    __shared__ float tile[32][33];
    int k0 = blockIdx.x * 32;
    int j0 = blockIdx.y * 32;
    int tx = threadIdx.x & 31;
    int ty = threadIdx.x >> 5;   // 0..7
#pragma unroll
    for (int i = 0; i < 32; i += 8)
        tile[ty + i][tx] = W[(size_t)(k0 + ty + i) * FOURH + (j0 + tx)];
    __syncthreads();
#pragma unroll
    for (int i = 0; i < 32; i += 8)
        Wt[(size_t)(j0 + ty + i) * DD + (k0 + tx)] = f2bf(tile[tx][ty + i]);
}

// ---------------- GEMM + fused LSTM epilogue ----------------
// m201-geometry: BM=BN=256 (cols interleaved: gate=c&3, h=h0+(c>>2)), BK=64,
// 512 thr = 8 waves (2M x 4N), per-wave 128x64, acc[8][4].
// LDS 128KB = 2 buffers x 64KB: A [256r][128B] at +0, B [256c][128B] at +32768.
// Swizzle (round-6 measured conflict-free): phys 16B slot s of row r holds k-chunk
// s^(r&7); pre-swizzled global source, linear LDS dest; frag reads slot
// ((lane>>4)^(lane&7)), k-half via ^64.
// 4 phases per K-tile (kh x nh quadrants); A-frags read once per k-half, reused
// across both n-phases (24 ds_read_b128 per 64 MFMA per wave = 0.375 KB/MFMA).
// Tile t stages tile t+1 (8 gload16) in phases 0-1; vmcnt(0) at phase-3 lead
// (~2.5 phases of slack -> drain hidden). One buffer swap per tile.

#define PRIO1 __builtin_amdgcn_s_setprio(1)
#define PRIO0 __builtin_amdgcn_s_setprio(0)
#define BARX __builtin_amdgcn_s_barrier()
#define LGKM0 asm volatile("s_waitcnt lgkmcnt(0)" ::: "memory")
#define SCHED0 __builtin_amdgcn_sched_barrier(0)
#define VMW0 asm volatile("s_waitcnt vmcnt(0)" ::: "memory")

#define RD_A(RB, KX) \
    _Pragma("unroll") for (int mi_ = 0; mi_ < 8; ++mi_) \
        aF[mi_] = *(const bf16x8*)(smem + (RB) + (aOff ^ (KX)) + mi_ * 2048);

#define RD_B(RB, KX, N0) \
    bF[0] = *(const bf16x8*)(smem + (RB) + 32768 + (bOff ^ (KX)) + (N0) * 2048); \
    bF[1] = *(const bf16x8*)(smem + (RB) + 32768 + (bOff ^ (KX)) + (N0 + 1) * 2048);

#define ST_A(SB, KO) \
    _Pragma("unroll") for (int l_ = 0; l_ < 4; ++l_) \
        gload16(aSrc + (size_t)l_ * 64 * DD + (KO), smem + (SB) + l_ * 8192 + ldst);

#define ST_B(SB, KO) \
    _Pragma("unroll") for (int l_ = 0; l_ < 4; ++l_) \
        gload16(bSrc + (size_t)l_ * 16 * DD + (KO), smem + (SB) + 32768 + l_ * 8192 + ldst);

#define MM(N0) \
    _Pragma("unroll") for (int ci_ = 0; ci_ < 2; ++ci_) \
        _Pragma("unroll") for (int mi_ = 0; mi_ < 8; ++mi_) \
            acc[mi_][(N0) + ci_] = __builtin_amdgcn_mfma_f32_16x16x32_bf16(aF[mi_], bF[ci_], acc[mi_][(N0) + ci_], 0, 0, 0);

#define TILE(RB, SB, KO, DOSTAGE) do { \
    bf16x8 aF[8], bF[2]; \
    RD_A(RB, 0) RD_B(RB, 0, 0) \
    if (DOSTAGE) { ST_A(SB, KO) } \
    BARX; LGKM0; SCHED0; PRIO1; MM(0) PRIO0; BARX; \
    RD_B(RB, 0, 2) \
    if (DOSTAGE) { ST_B(SB, KO) } \
    BARX; LGKM0; SCHED0; PRIO1; MM(2) PRIO0; BARX; \
    RD_A(RB, 64) RD_B(RB, 64, 0) \
    BARX; LGKM0; SCHED0; PRIO1; MM(0) PRIO0; BARX; \
    RD_B(RB, 64, 2) \
    VMW0; \
    BARX; LGKM0; SCHED0; PRIO1; MM(2) PRIO0; BARX; \
} while (0)

__global__ __launch_bounds__(512, 2) void gemm_lstm_kernel(
    const unsigned short* __restrict__ agg,
    const unsigned short* __restrict__ Wt,
    const float* __restrict__ bias,
    const float* __restrict__ c_cur,
    float* __restrict__ out)
{
    __shared__ char smem[131072];        // 2 x 64KB

    const int tid = threadIdx.x;
    const int lane = tid & 63;
    const int wave = tid >> 6;          // 0..7
    const int waveM = wave >> 2;        // 0..1  (128 rows each)
    const int waveN = wave & 3;         // 0..3  (64 interleaved cols = 16 h each)

    const int orig = blockIdx.x;        // 632 = 8 * 79
    const int f = (orig & 7) * 79 + (orig >> 3);
    const int blockM = f >> 3;          // 0..78 (8 consecutive f share one A-tile)
    const int h0 = (f & 7) * 64;
    const int m0 = blockM * 256;

    // fragment read offsets (kh=0); kh=1 via ^64 (slot s holds chunk s^(r&7))
    const int slot = ((lane >> 4) ^ (lane & 7)) * 16;
    const int aOff = (waveM * 128 + (lane & 15)) * 128 + slot;
    const int bOff = (waveN * 64 + (lane & 15)) * 128 + slot;

    // staging source pointers: chunk q = l*512+tid -> row/col q>>3, slot q&7,
    // global k-chunk (q&7)^((q>>3)&7)  [l*64 / l*16 multiples drop out of &7]
    const int koff = 8 * ((tid & 7) ^ ((tid >> 3) & 7));
    const unsigned short* aSrc = agg + (size_t)(m0 + (tid >> 3)) * DD + koff;
    const unsigned short* bSrc = Wt + (size_t)(((tid >> 3) & 3) * 512 + h0 + (tid >> 5)) * DD + koff;
    const int ldst = tid * 16;

    f32x4 acc[8][4];
#pragma unroll
    for (int i = 0; i < 8; ++i)
#pragma unroll
        for (int j = 0; j < 4; ++j) {
            f32x4 z = {0.f, 0.f, 0.f, 0.f};
            acc[i][j] = z;
        }

    // prologue: stage tile 0 into buf0
    { ST_A(0, 0) ST_B(0, 0) }
    VMW0;
    BARX;

    // 16 K-tiles; tile t reads buf[t&1], stages t+1 into buf[(t+1)&1]
    for (int t2 = 0; t2 < 8; ++t2) {
        TILE(0,     65536, (size_t)(2 * t2 + 1) * 64, true);
        TILE(65536, 0,     (size_t)(2 * t2 + 2) * 64, t2 != 7);
    }

    // ---- epilogue: quad transpose -> LSTM math -> LDS-staged coalesced stores ----
    float* fb = (float*)smem;            // [256][64] f32 (64KB), h-XOR ((row&7)<<2)
    const int a = lane & 3;
    float cnewR[8][4];
#pragma unroll
    for (int mi = 0; mi < 8; ++mi) {
#pragma unroll
        for (int ci = 0; ci < 4; ++ci) {
            float v0 = acc[mi][ci][0], v1 = acc[mi][ci][1];
            float v2 = acc[mi][ci][2], v3 = acc[mi][ci][3];
            bool hi1 = (lane & 2) != 0;
            float s0 = hi1 ? v0 : v2;
            float s1 = hi1 ? v1 : v3;
            float r0 = __shfl_xor(s0, 2, 64);
            float r1 = __shfl_xor(s1, 2, 64);
            if (hi1) { v0 = r0; v1 = r1; } else { v2 = r0; v3 = r1; }
            bool hi0 = (lane & 1) != 0;
            float t0 = hi0 ? v0 : v1;
            float t1 = hi0 ? v2 : v3;
            float q0 = __shfl_xor(t0, 1, 64);
            float q1 = __shfl_xor(t1, 1, 64);
            if (hi0) { v0 = q0; v2 = q1; } else { v1 = q0; v3 = q1; }
            // v0..v3 = pre-bias conv for gates i,f,o,g at (row, h)
            int rl = waveM * 128 + mi * 16 + ((lane >> 4) << 2) + a;
            int hl = waveN * 16 + ci * 4 + ((lane & 15) >> 2);
            int m = m0 + rl;
            int hh = h0 + hl;
            float iv = sigmoidf_(v0 + bias[hh]);
            float fv = sigmoidf_(v1 + bias[512 + hh]);
            float ov = sigmoidf_(v2 + bias[1024 + hh]);
            float gv = tanhf_(v3 + bias[1536 + hh]);
            float cold = (m < MT) ? c_cur[(size_t)m * 512 + hh] : 0.f;
            float cnew = fv * cold + iv * gv;
            float hnew = ov * tanhf_(cnew);
            cnewR[mi][ci] = cnew;
            fb[rl * 64 + (hl ^ ((rl & 7) << 2))] = hnew;
        }
    }
    __syncthreads();
#pragma unroll
    for (int q = 0; q < 8; ++q) {
        int cid = q * 512 + tid;
        int row = cid >> 4;
        int c16 = cid & 15;
        int m = m0 + row;
        float4 v = *(const float4*)&fb[row * 64 + ((c16 * 4) ^ ((row & 7) << 2))];
        if (m < MT) *(float4*)&out[(size_t)m * 512 + h0 + c16 * 4] = v;
    }
    __syncthreads();
#pragma unroll
    for (int mi = 0; mi < 8; ++mi)
#pragma unroll
        for (int ci = 0; ci < 4; ++ci) {
            int rl = waveM * 128 + mi * 16 + ((lane >> 4) << 2) + a;
            int hl = waveN * 16 + ci * 4 + ((lane & 15) >> 2);
            fb[rl * 64 + (hl ^ ((rl & 7) << 2))] = cnewR[mi][ci];
        }
    __syncthreads();
#pragma unroll
    for (int q = 0; q < 8; ++q) {
        int cid = q * 512 + tid;
        int row = cid >> 4;
        int c16 = cid & 15;
        int m = m0 + row;
        float4 v = *(const float4*)&fb[row * 64 + ((c16 * 4) ^ ((row & 7) << 2))];
        if (m < MT) *(float4*)&out[(size_t)10240000 + (size_t)m * 512 + h0 + c16 * 4] = v;
    }
}

extern "C" void kernel_launch(void* const* d_in, const int* in_sizes, int n_in,
                              void* d_out, int out_size, void* d_ws, size_t ws_size,
                              hipStream_t stream) {
    const float* x    = (const float*)d_in[0];
    const float* h    = (const float*)d_in[1];
    const float* c    = (const float*)d_in[2];
    const int*   ei   = (const int*)d_in[3];
    const float* W    = (const float*)d_in[4];
    const float* bias = (const float*)d_in[5];
    float* out = (float*)d_out;
    (void)in_sizes; (void)n_in; (void)out_size; (void)ws_size;

    const int* src = ei;
    const int* dst = ei + EE;

    char* ws = (char*)d_ws;
    size_t off = 0;
    auto alloc = [&](size_t bytes) -> void* {
        void* p = ws + off;
        off = (off + bytes + 255) & ~(size_t)255;
        return p;
    };
    unsigned short* agg = (unsigned short*)alloc((size_t)MPAD * DD * 2);
    unsigned short* Wt  = (unsigned short*)alloc((size_t)FOURH * DD * 2);
    unsigned short* xhc = (unsigned short*)alloc((size_t)NN * 2048 * 2);
    int*   counts  = (int*)alloc(NN * 4);
    int*   offsets = (int*)alloc((NN + 1) * 4);
    int*   cursor  = (int*)alloc(NN * 4);
    float* dinv    = (float*)alloc(NN * 4);
    float* invdeg  = (float*)alloc(NN * 4);
    int*   csr     = (int*)alloc(EE * 4);

    hipMemsetAsync(counts, 0, NN * 4, stream);
    count_kernel<<<(EE + 255) / 256, 256, 0, stream>>>(dst, counts);
    scan_kernel<<<1, 1024, 0, stream>>>(counts, offsets, cursor, dinv, invdeg);
    fill_kernel<<<(EE + 255) / 256, 256, 0, stream>>>(src, dst, cursor, csr);
    convert_kernel<<<NN, 256, 0, stream>>>(x, h, xhc);
    wt_kernel<<<dim3(32, 64), 256, 0, stream>>>(W, Wt);
    padzero_kernel<<<224, 256, 0, stream>>>(agg);
    agg_kernel<<<NN, 256, 0, stream>>>(xhc, csr, offsets, dinv, invdeg, agg);
    gemm_lstm_kernel<<<632, 512, 0, stream>>>(agg, Wt, bias, c, out);
}

// Round 8
// 295.847 us; speedup vs baseline: 1.0686x; 1.0686x over previous
//
#include <hip/hip_runtime.h>

#define NN 10000
#define EE 160000
#define DD 1024          // D_IN + H
#define FOURH 2048
#define HH 512
#define MT 20000         // B*N
#define MPAD 20224       // 158 * 128

typedef __attribute__((ext_vector_type(8))) short bf16x8;
typedef __attribute__((ext_vector_type(4))) float f32x4;

typedef __attribute__((address_space(1))) void gvoid;
typedef __attribute__((address_space(3))) void lvoid;

__device__ inline void gload16(const void* g, void* l) {
    __builtin_amdgcn_global_load_lds((gvoid*)g, (lvoid*)l, 16, 0, 0);
}

__device__ inline unsigned short f2bf(float f) {
    unsigned u = __float_as_uint(f);
    u += 0x7fff + ((u >> 16) & 1);   // RNE
    return (unsigned short)(u >> 16);
}

__device__ inline float bflo(unsigned u) { return __uint_as_float(u << 16); }
__device__ inline float bfhi(unsigned u) { return __uint_as_float(u & 0xffff0000u); }

__device__ inline float sigmoidf_(float x) {
    x = fminf(fmaxf(x, -30.f), 30.f);
    return 1.f / (1.f + __expf(-x));
}
__device__ inline float tanhf_(float x) {
    x = fminf(fmaxf(x, -15.f), 15.f);
    float e = __expf(2.f * x);
    return (e - 1.f) / (e + 1.f);
}

// ---------------- CSR build ----------------

__global__ void count_kernel(const int* __restrict__ dst, int* __restrict__ counts) {
    int e = blockIdx.x * blockDim.x + threadIdx.x;
    if (e < EE) atomicAdd(&counts[dst[e]], 1);
}

__global__ void scan_kernel(const int* __restrict__ counts, int* __restrict__ offsets,
                            int* __restrict__ cursor, float* __restrict__ dinv,
                            float* __restrict__ invdeg) {
    __shared__ int s[1024];
    int tid = threadIdx.x;
    int running = 0;
    if (tid == 0) offsets[0] = 0;
    for (int base = 0; base < NN; base += 1024) {
        int i = base + tid;
        int v = (i < NN) ? counts[i] : 0;
        s[tid] = v;
        __syncthreads();
        for (int off = 1; off < 1024; off <<= 1) {
            int t = (tid >= off) ? s[tid - off] : 0;
            __syncthreads();
            s[tid] += t;
            __syncthreads();
        }
        int incl = s[tid];
        if (i < NN) {
            offsets[i + 1] = running + incl;
            cursor[i] = running + incl - v;   // exclusive
            float deg = (float)(v + 1);
            dinv[i] = rsqrtf(deg);
            invdeg[i] = 1.0f / deg;
        }
        running += s[1023];
        __syncthreads();
    }
}

__global__ void fill_kernel(const int* __restrict__ src, const int* __restrict__ dst,
                            int* __restrict__ cursor, int* __restrict__ csr_src) {
    int e = blockIdx.x * blockDim.x + threadIdx.x;
    if (e < EE) {
        int p = atomicAdd(&cursor[dst[e]], 1);
        csr_src[p] = src[e];
    }
}

// ---------------- x,h -> packed bf16 rows xhc[n][2048] ----------------

__global__ __launch_bounds__(256) void convert_kernel(
    const float* __restrict__ x, const float* __restrict__ h,
    unsigned short* __restrict__ xhc)
{
    int n = blockIdx.x;
    int t = threadIdx.x;
    int sec = t >> 6;        // 0..3
    int li = t & 63;         // 8 floats each
    const float* srcp;
    if (sec == 0)      srcp = x + (size_t)n * 512 + li * 8;
    else if (sec == 1) srcp = h + (size_t)n * 512 + li * 8;
    else if (sec == 2) srcp = x + (size_t)(NN + n) * 512 + li * 8;
    else               srcp = h + (size_t)(NN + n) * 512 + li * 8;
    float4 v0 = *(const float4*)srcp;
    float4 v1 = *(const float4*)(srcp + 4);
    uint4 o;
    o.x = f2bf(v0.x) | ((unsigned)f2bf(v0.y) << 16);
    o.y = f2bf(v0.z) | ((unsigned)f2bf(v0.w) << 16);
    o.z = f2bf(v1.x) | ((unsigned)f2bf(v1.y) << 16);
    o.w = f2bf(v1.z) | ((unsigned)f2bf(v1.w) << 16);
    *(uint4*)(xhc + (size_t)n * 2048 + t * 8) = o;
}

__global__ void padzero_kernel(unsigned short* __restrict__ agg) {
    int idx = blockIdx.x * 256 + threadIdx.x;      // 224 rows * 1024 / 4 = 57344 ushort4
    ushort4* p = (ushort4*)(agg + (size_t)MT * DD);
    if (idx < 57344) p[idx] = make_ushort4(0, 0, 0, 0);
}

// ---------------- aggregation (bf16 gather, fp32 accumulate) ----------------

__global__ __launch_bounds__(256) void agg_kernel(
    const unsigned short* __restrict__ xhc,
    const int* __restrict__ csr_src, const int* __restrict__ offsets,
    const float* __restrict__ dinv, const float* __restrict__ invdeg,
    unsigned short* __restrict__ agg)
{
    int n = blockIdx.x;
    int t = threadIdx.x;                 // 8 bf16 per thread of the 2048-wide row
    const unsigned short* base = xhc + t * 8;
    float a0 = 0, a1 = 0, a2 = 0, a3 = 0, a4 = 0, a5 = 0, a6 = 0, a7 = 0;
    float dn = dinv[n];
    int beg = offsets[n], end = offsets[n + 1];
    for (int j = beg; j < end; ++j) {
        int s = csr_src[j];
        float w = dn * dinv[s];
        uint4 v = *(const uint4*)(base + (size_t)s * 2048);
        a0 += w * bflo(v.x); a1 += w * bfhi(v.x);
        a2 += w * bflo(v.y); a3 += w * bfhi(v.y);
        a4 += w * bflo(v.z); a5 += w * bfhi(v.z);
        a6 += w * bflo(v.w); a7 += w * bfhi(v.w);
    }
    float sw = invdeg[n];
    {
        uint4 v = *(const uint4*)(base + (size_t)n * 2048);
        a0 += sw * bflo(v.x); a1 += sw * bfhi(v.x);
        a2 += sw * bflo(v.y); a3 += sw * bfhi(v.y);
        a4 += sw * bflo(v.z); a5 += sw * bfhi(v.z);
        a6 += sw * bflo(v.w); a7 += sw * bfhi(v.w);
    }
    uint4 o;
    o.x = f2bf(a0) | ((unsigned)f2bf(a1) << 16);
    o.y = f2bf(a2) | ((unsigned)f2bf(a3) << 16);
    o.z = f2bf(a4) | ((unsigned)f2bf(a5) << 16);
    o.w = f2bf(a6) | ((unsigned)f2bf(a7) << 16);
    int bsel = t >> 7;                   // batch
    int d = (t & 127) * 8;               // dim within 1024
    *(uint4*)(agg + ((size_t)(bsel * NN + n)) * DD + d) = o;
}

// ---------------- W transpose -> bf16 (Wt[j][k]) ----------------

__global__ __launch_bounds__(256) void wt_kernel(const float* __restrict__ W,
                                                 unsigned short* __restrict__ Wt) {
    __shared__ float tile[32][33];
    int k0 = blockIdx.x * 32;
    int j0 = blockIdx.y * 32;
    int tx = threadIdx.x & 31;
    int ty = threadIdx.x >> 5;   // 0..7
#pragma unroll
    for (int i = 0; i < 32; i += 8)
        tile[ty + i][tx] = W[(size_t)(k0 + ty + i) * FOURH + (j0 + tx)];
    __syncthreads();
#pragma unroll
    for (int i = 0; i < 32; i += 8)
        Wt[(size_t)(j0 + ty + i) * DD + (k0 + tx)] = f2bf(tile[tx][ty + i]);
}

// ---------------- GEMM + fused LSTM epilogue ----------------
// m97-mechanism build: 128x128 tile (cols interleaved: gate=c&3, h=h0+(c>>2)),
// BK=64, 256 thr = 4 waves (2M x 2N), per-wave 64x64, acc[4][4], single-buffered
// 32KB LDS -> multiple blocks/CU overlap hides the per-tile vmcnt(0)+barrier drain
// (m114). 2-barrier compiler-scheduled loop (no inline asm). Swizzle = r6-measured
// conflict-free: 128B rows, phys 16B slot s of row r holds k-chunk s^(r&7)
// (pre-swizzled global source, linear LDS dest); frag slot ((lane>>4)^(lane&7)),
// k-half via ^64. Grid 2528 = 8 XCD chunks x 316, h-tile-fastest within chunk
// (16 consecutive blocks share one 256KB A-panel in L2).

__global__ __launch_bounds__(256, 4) void gemm_lstm_kernel(
    const unsigned short* __restrict__ agg,
    const unsigned short* __restrict__ Wt,
    const float* __restrict__ bias,
    const float* __restrict__ c_cur,
    float* __restrict__ out)
{
    __shared__ char smem[32768];        // A [128][128B] at 0, B [128][128B] at 16384

    const int tid = threadIdx.x;
    const int lane = tid & 63;
    const int wave = tid >> 6;          // 0..3
    const int waveM = wave >> 1;        // 0..1 (64 rows each)
    const int waveN = wave & 1;         // 0..1 (64 interleaved cols = 16 h each)

    const int orig = blockIdx.x;        // 2528 = 8 * 316
    const int f = (orig & 7) * 316 + (orig >> 3);
    const int blockM = f >> 4;          // 0..157
    const int h0 = (f & 15) * 32;
    const int m0 = blockM * 128;

    // fragment read offsets (kh=0); kh=1 via ^64 (slot s holds chunk s^(r&7))
    const int slot = ((lane >> 4) ^ (lane & 7)) * 16;
    const int aOff = (waveM * 64 + (lane & 15)) * 128 + slot;
    const int bOff = 16384 + (waveN * 64 + (lane & 15)) * 128 + slot;

    // staging: chunk q = l*256+tid -> row/col l*32+(tid>>3), slot tid&7,
    // global k-chunk (tid&7)^((tid>>3)&7)   [l*32 drops out of &7]
    const int koff = 8 * ((tid & 7) ^ ((tid >> 3) & 7));
    const unsigned short* aSrc = agg + (size_t)(m0 + (tid >> 3)) * DD + koff;
    const unsigned short* bSrc = Wt + (size_t)(((tid >> 3) & 3) * 512 + h0 + (tid >> 5)) * DD + koff;

    f32x4 acc[4][4];
#pragma unroll
    for (int i = 0; i < 4; ++i)
#pragma unroll
        for (int j = 0; j < 4; ++j) {
            f32x4 z = {0.f, 0.f, 0.f, 0.f};
            acc[i][j] = z;
        }

    for (int kt = 0; kt < 16; ++kt) {
        __syncthreads();
#pragma unroll
        for (int l = 0; l < 4; ++l)
            gload16(aSrc + (size_t)l * 32 * DD + kt * 64, smem + l * 4096 + tid * 16);
#pragma unroll
        for (int l = 0; l < 4; ++l)
            gload16(bSrc + (size_t)l * 8 * DD + kt * 64, smem + 16384 + l * 4096 + tid * 16);
        __syncthreads();
#pragma unroll
        for (int ksub = 0; ksub < 2; ++ksub) {
            const int kx = ksub * 64;
            bf16x8 aF[4], bF[4];
#pragma unroll
            for (int mi = 0; mi < 4; ++mi)
                aF[mi] = *(const bf16x8*)(smem + (aOff ^ kx) + mi * 2048);
#pragma unroll
            for (int ci = 0; ci < 4; ++ci)
                bF[ci] = *(const bf16x8*)(smem + (bOff ^ kx) + ci * 2048);
#pragma unroll
            for (int ci = 0; ci < 4; ++ci)
#pragma unroll
                for (int mi = 0; mi < 4; ++mi)
                    acc[mi][ci] = __builtin_amdgcn_mfma_f32_16x16x32_bf16(aF[mi], bF[ci], acc[mi][ci], 0, 0, 0);
        }
    }

    // ---- epilogue: quad transpose -> LSTM math -> LDS-staged coalesced stores ----
    __syncthreads();                     // all LDS reads done; reuse smem
    float* fb = (float*)smem;            // [128][32] f32 (16KB), h-XOR ((row&7)<<2)
    const int a = lane & 3;
    float cnewR[4][4];
#pragma unroll
    for (int mi = 0; mi < 4; ++mi) {
#pragma unroll
        for (int ci = 0; ci < 4; ++ci) {
            float v0 = acc[mi][ci][0], v1 = acc[mi][ci][1];
            float v2 = acc[mi][ci][2], v3 = acc[mi][ci][3];
            bool hi1 = (lane & 2) != 0;
            float s0 = hi1 ? v0 : v2;
            float s1 = hi1 ? v1 : v3;
            float r0 = __shfl_xor(s0, 2, 64);
            float r1 = __shfl_xor(s1, 2, 64);
            if (hi1) { v0 = r0; v1 = r1; } else { v2 = r0; v3 = r1; }
            bool hi0 = (lane & 1) != 0;
            float t0 = hi0 ? v0 : v1;
            float t1 = hi0 ? v2 : v3;
            float q0 = __shfl_xor(t0, 1, 64);
            float q1 = __shfl_xor(t1, 1, 64);
            if (hi0) { v0 = q0; v2 = q1; } else { v1 = q0; v3 = q1; }
            // v0..v3 = pre-bias conv for gates i,f,o,g at (row, h)
            int rl = waveM * 64 + mi * 16 + ((lane >> 4) << 2) + a;
            int hl = waveN * 16 + ci * 4 + ((lane & 15) >> 2);
            int m = m0 + rl;
            int hh = h0 + hl;
            float iv = sigmoidf_(v0 + bias[hh]);
            float fv = sigmoidf_(v1 + bias[512 + hh]);
            float ov = sigmoidf_(v2 + bias[1024 + hh]);
            float gv = tanhf_(v3 + bias[1536 + hh]);
            float cold = (m < MT) ? c_cur[(size_t)m * 512 + hh] : 0.f;
            float cnew = fv * cold + iv * gv;
            float hnew = ov * tanhf_(cnew);
            cnewR[mi][ci] = cnew;
            fb[rl * 32 + (hl ^ ((rl & 7) << 2))] = hnew;
        }
    }
    __syncthreads();
#pragma unroll
    for (int q = 0; q < 4; ++q) {
        int cid = q * 256 + tid;
        int row = cid >> 3;
        int c8 = cid & 7;
        int m = m0 + row;
        float4 v = *(const float4*)&fb[row * 32 + ((c8 * 4) ^ ((row & 7) << 2))];
        if (m < MT) *(float4*)&out[(size_t)m * 512 + h0 + c8 * 4] = v;
    }
    __syncthreads();
#pragma unroll
    for (int mi = 0; mi < 4; ++mi)
#pragma unroll
        for (int ci = 0; ci < 4; ++ci) {
            int rl = waveM * 64 + mi * 16 + ((lane >> 4) << 2) + a;
            int hl = waveN * 16 + ci * 4 + ((lane & 15) >> 2);
            fb[rl * 32 + (hl ^ ((rl & 7) << 2))] = cnewR[mi][ci];
        }
    __syncthreads();
#pragma unroll
    for (int q = 0; q < 4; ++q) {
        int cid = q * 256 + tid;
        int row = cid >> 3;
        int c8 = cid & 7;
        int m = m0 + row;
        float4 v = *(const float4*)&fb[row * 32 + ((c8 * 4) ^ ((row & 7) << 2))];
        if (m < MT) *(float4*)&out[(size_t)10240000 + (size_t)m * 512 + h0 + c8 * 4] = v;
    }
}

extern "C" void kernel_launch(void* const* d_in, const int* in_sizes, int n_in,
                              void* d_out, int out_size, void* d_ws, size_t ws_size,
                              hipStream_t stream) {
    const float* x    = (const float*)d_in[0];
    const float* h    = (const float*)d_in[1];
    const float* c    = (const float*)d_in[2];
    const int*   ei   = (const int*)d_in[3];
    const float* W    = (const float*)d_in[4];
    const float* bias = (const float*)d_in[5];
    float* out = (float*)d_out;
    (void)in_sizes; (void)n_in; (void)out_size; (void)ws_size;

    const int* src = ei;
    const int* dst = ei + EE;

    char* ws = (char*)d_ws;
    size_t off = 0;
    auto alloc = [&](size_t bytes) -> void* {
        void* p = ws + off;
        off = (off + bytes + 255) & ~(size_t)255;
        return p;
    };
    unsigned short* agg = (unsigned short*)alloc((size_t)MPAD * DD * 2);
    unsigned short* Wt  = (unsigned short*)alloc((size_t)FOURH * DD * 2);
    unsigned short* xhc = (unsigned short*)alloc((size_t)NN * 2048 * 2);
    int*   counts  = (int*)alloc(NN * 4);
    int*   offsets = (int*)alloc((NN + 1) * 4);
    int*   cursor  = (int*)alloc(NN * 4);
    float* dinv    = (float*)alloc(NN * 4);
    float* invdeg  = (float*)alloc(NN * 4);
    int*   csr     = (int*)alloc(EE * 4);

    hipMemsetAsync(counts, 0, NN * 4, stream);
    count_kernel<<<(EE + 255) / 256, 256, 0, stream>>>(dst, counts);
    scan_kernel<<<1, 1024, 0, stream>>>(counts, offsets, cursor, dinv, invdeg);
    fill_kernel<<<(EE + 255) / 256, 256, 0, stream>>>(src, dst, cursor, csr);
    convert_kernel<<<NN, 256, 0, stream>>>(x, h, xhc);
    wt_kernel<<<dim3(32, 64), 256, 0, stream>>>(W, Wt);
    padzero_kernel<<<224, 256, 0, stream>>>(agg);
    agg_kernel<<<NN, 256, 0, stream>>>(xhc, csr, offsets, dinv, invdeg, agg);
    gemm_lstm_kernel<<<2528, 256, 0, stream>>>(agg, Wt, bias, c, out);
}